// Round 3
// baseline (335.862 us; speedup 1.0000x reference)
//
#include <hip/hip_runtime.h>

// Problem constants (fixed by setup_inputs)
constexpr int B = 4;
constexpr int N = 768;
constexpr int D = 16;           // per-node embedding dim
constexpr int E = 12288;        // edges per batch
constexpr int NN = N * N;       // 589824 pairs per batch
constexpr int PAIRS = B * NN;   // 2,359,296
constexpr long long EE_FLOATS = (long long)PAIRS * 2 * D;  // 75,497,472

// Native clang vector type — required by __builtin_nontemporal_store
// (HIP's float4 is a class and is rejected).
typedef float v4f __attribute__((ext_vector_type(4)));

// Fused kernel: one block per (b, i) row -> writes 768 pairs of
// edge_embeddings (96 KB), 768 logits, 768 truth-zeros.
// Phase 1 layout trick: with 256 threads and 8 float4 per pair,
// q = k & 7 == t & 7 is loop-invariant per thread. Lanes with q<4
// store the hoisted row-i quarter; lanes with q>=4 stream row-j quarters.
__global__ __launch_bounds__(256) void fused_row_kernel(
    const v4f* __restrict__ emb4,      // [B*N*4] v4f (row = 4 quarters)
    const float* __restrict__ W,       // [32]
    const float* __restrict__ bias,    // [1]
    v4f* __restrict__ ee4,             // [PAIRS*8]
    float* __restrict__ logits,        // [PAIRS]
    float* __restrict__ truth)         // [PAIRS]
{
    const int blk = blockIdx.x;        // 0 .. B*N-1
    const int b = blk / N;
    const int i = blk - b * N;
    const int t = threadIdx.x;

    const v4f* embB = emb4 + (b * N) * 4;      // batch-b row base

    // ---- Phase 1: edge_embeddings for row i ----
    const long long base = ((long long)(b * NN + i * N)) * 8;  // in v4f units
    const int q = t & 7;               // loop-invariant quarter id
    v4f vi = {0.f, 0.f, 0.f, 0.f};
    if (q < 4) vi = embB[i * 4 + q];   // hoisted broadcast value
    const int jq = q - 4;
#pragma unroll
    for (int iter = 0; iter < (N * 8) / 256; ++iter) {   // 24 iterations
        const int k = t + iter * 256;                    // 0 .. 6143
        v4f v;
        if (q < 4) {
            v = vi;
        } else {
            const int j = k >> 3;                        // row j
            v = embB[j * 4 + jq];
        }
        __builtin_nontemporal_store(v, &ee4[base + k]);
    }

    // ---- Phase 2: logits + truth zeros for row i ----
    const v4f i0 = embB[i * 4 + 0], i1 = embB[i * 4 + 1],
              i2 = embB[i * 4 + 2], i3 = embB[i * 4 + 3];
    const float acc_i =
        i0.x * W[0]  + i0.y * W[1]  + i0.z * W[2]  + i0.w * W[3]  +
        i1.x * W[4]  + i1.y * W[5]  + i1.z * W[6]  + i1.w * W[7]  +
        i2.x * W[8]  + i2.y * W[9]  + i2.z * W[10] + i2.w * W[11] +
        i3.x * W[12] + i3.y * W[13] + i3.z * W[14] + i3.w * W[15] +
        bias[0];
    const long long lbase = (long long)b * NN + (long long)i * N;
#pragma unroll
    for (int rep = 0; rep < N / 256; ++rep) {            // 3 iterations
        const int j = t + rep * 256;
        const v4f j0 = embB[j * 4 + 0], j1 = embB[j * 4 + 1],
                  j2 = embB[j * 4 + 2], j3 = embB[j * 4 + 3];
        const float acc = acc_i +
            j0.x * W[16] + j0.y * W[17] + j0.z * W[18] + j0.w * W[19] +
            j1.x * W[20] + j1.y * W[21] + j1.z * W[22] + j1.w * W[23] +
            j2.x * W[24] + j2.y * W[25] + j2.z * W[26] + j2.w * W[27] +
            j3.x * W[28] + j3.y * W[29] + j3.z * W[30] + j3.w * W[31];
        const float diff =
            fabsf(i0.x - j0.x) + fabsf(i0.y - j0.y) + fabsf(i0.z - j0.z) + fabsf(i0.w - j0.w) +
            fabsf(i1.x - j1.x) + fabsf(i1.y - j1.y) + fabsf(i1.z - j1.z) + fabsf(i1.w - j1.w) +
            fabsf(i2.x - j2.x) + fabsf(i2.y - j2.y) + fabsf(i2.z - j2.z) + fabsf(i2.w - j2.w) +
            fabsf(i3.x - j3.x) + fabsf(i3.y - j3.y) + fabsf(i3.z - j3.z) + fabsf(i3.w - j3.w);
        __builtin_nontemporal_store((diff != 0.f) ? acc : -10.0f, &logits[lbase + j]);
        __builtin_nontemporal_store(0.0f, &truth[lbase + j]);
    }
}

// K3: scatter ground-truth edges (after truth zeroing; same stream => ordered).
// edges layout [B, 2, E]; duplicates idempotent (plain store of 1.0).
__global__ void truth_scatter_kernel(const int* __restrict__ edges,
                                     float* __restrict__ truth) {
    int t = blockIdx.x * blockDim.x + threadIdx.x;
    if (t >= B * E) return;
    int b = t / E;
    int e = t - b * E;
    int src = edges[b * 2 * E + e];
    int dst = edges[b * 2 * E + E + e];
    truth[(long long)b * NN + src * N + dst] = 1.0f;
}

extern "C" void kernel_launch(void* const* d_in, const int* in_sizes, int n_in,
                              void* d_out, int out_size, void* d_ws, size_t ws_size,
                              hipStream_t stream) {
    const v4f* emb4 = (const v4f*)d_in[0];             // [B,N,16] fp32
    const int* edges = (const int*)d_in[1];            // [B,2,E]
    const float* W = (const float*)d_in[2];            // [32]
    const float* bias = (const float*)d_in[3];         // [1]

    float* out = (float*)d_out;
    float* ee = out;
    float* logits = out + EE_FLOATS;
    float* truth = out + EE_FLOATS + (long long)PAIRS;

    // Fused edge_embeddings + logits + truth-zero: one block per (b, i)
    fused_row_kernel<<<B * N, 256, 0, stream>>>(emb4, W, bias,
                                                (v4f*)ee, logits, truth);

    // Edge scatter into truth
    {
        int threads = 256;
        int blocks = (B * E + threads - 1) / threads;
        truth_scatter_kernel<<<blocks, threads, 0, stream>>>(edges, truth);
    }
}